// Round 1
// 253.197 us; speedup vs baseline: 1.1346x; 1.1346x over previous
//
#include <hip/hip_runtime.h>

// WassersteinLoss: per-row W1 = (1/N) * sum_i |sort(u)[i] - sort(v)[i]|, mean over rows.
// R5: ascending-only "mirror" bitonic + 2-op compare-select.
//   vs R4 (287 us harness / ~200 us kernel, VALUBusy 89%, HBM 4% -> VALU-bound):
//   1) classic two-ascending-halves merge: first pass compares g <-> g^(S-1)
//      (mirror), then xor-descend S/4..1, ALL comparisons keep min at lower
//      index. Removes every sign-negation xor pass (~900 VALU ops/thread).
//      Mirror partner t^X with register reversal k->31-k (reversal is free:
//      it's a compile-time register-index permutation).
//   2) compare-select CE: ((o<x) != keep_min) ? x : o
//      -> v_cmp (VALU) + s_xor_b64 (SALU, idle pipe) + v_cndmask (VALU)
//      = 2 VALU instead of min+max+cndmask = 3 VALU. Exchanges stay on
//      DPP (m=1,2) / ds_bpermute (m>=4, DS pipe) / LDS (t^64 boundary).
//   Cross-pass count unchanged (28); predicted ~25% VALU reduction.

constexpr int N_ELEM  = 4096;
constexpr int V       = 32;     // elements per thread per array
constexpr int THREADS = 256;    // 4 waves = 2 rows per block

// ---- compare-select: keep min(x,o) if keep_min, else max(x,o).
//      ((o<x) != keep_min) ? x : o  — one compare, one mask-xor, one select.
__device__ __forceinline__ float ce2(float x, float o, bool keep_min) {
    return ((o < x) != keep_min) ? x : o;
}

// ---- in-register ascending merge of S-blocks: mirror + descend S/4..1 ----
template<int S>
__device__ __forceinline__ void reg_merge(float r[V]) {
    #pragma unroll
    for (int k = 0; k < V; ++k) {
        if ((k & (S >> 1)) == 0) {
            const int j = k ^ (S - 1);          // complement low bits = mirror partner
            const float a = r[k], b = r[j];
            r[k] = fminf(a, b);
            r[j] = fmaxf(a, b);
        }
    }
    #pragma unroll
    for (int s = S >> 2; s >= 1; s >>= 1) {
        #pragma unroll
        for (int k = 0; k < V; ++k) {
            if ((k & s) == 0) {
                const float a = r[k], b = r[k + s];
                r[k]     = fminf(a, b);
                r[k + s] = fmaxf(a, b);
            }
        }
    }
}

// ---- ascending register descend, strides 16..1 (tail of every cross stage) ----
__device__ __forceinline__ void reg_tail_asc(float r[V]) {
    #pragma unroll
    for (int s = 16; s >= 1; s >>= 1) {
        #pragma unroll
        for (int k = 0; k < V; ++k) {
            if ((k & s) == 0) {
                const float a = r[k], b = r[k + s];
                r[k]     = fminf(a, b);
                r[k + s] = fmaxf(a, b);
            }
        }
    }
}

template<int CTRL>
__device__ __forceinline__ float dpp_x(float x) {
    return __int_as_float(__builtin_amdgcn_mov_dpp(__float_as_int(x), CTRL, 0xF, 0xF, true));
}
__device__ __forceinline__ float bperm_x(int pa, float x) {
    return __int_as_float(__builtin_amdgcn_ds_bpermute(pa, __float_as_int(x)));
}

// ---- descend xor pass, lane partner lane^M, keep_min at (lane&M)==0 ----
template<int M>
__device__ __forceinline__ void xor_pass(float ru[V], float rv[V], int lane) {
    const bool keep_min = (lane & M) == 0;
    if constexpr (M == 1) {
        #pragma unroll
        for (int k = 0; k < V; ++k) {
            ru[k] = ce2(ru[k], dpp_x<0xB1>(ru[k]), keep_min);
            rv[k] = ce2(rv[k], dpp_x<0xB1>(rv[k]), keep_min);
        }
    } else if constexpr (M == 2) {
        #pragma unroll
        for (int k = 0; k < V; ++k) {
            ru[k] = ce2(ru[k], dpp_x<0x4E>(ru[k]), keep_min);
            rv[k] = ce2(rv[k], dpp_x<0x4E>(rv[k]), keep_min);
        }
    } else {
        const int pa = (lane ^ M) << 2;
        #pragma unroll
        for (int k = 0; k < V; ++k) {
            ru[k] = ce2(ru[k], bperm_x(pa, ru[k]), keep_min);
            rv[k] = ce2(rv[k], bperm_x(pa, rv[k]), keep_min);
        }
    }
}

// ---- cross descend m=MMAX..1 then register tail (strides 16..1) ----
template<int MMAX>
__device__ __forceinline__ void cross_descend(float ru[V], float rv[V], int lane) {
    if constexpr (MMAX >= 32) xor_pass<32>(ru, rv, lane);
    if constexpr (MMAX >= 16) xor_pass<16>(ru, rv, lane);
    if constexpr (MMAX >= 8)  xor_pass<8>(ru, rv, lane);
    if constexpr (MMAX >= 4)  xor_pass<4>(ru, rv, lane);
    if constexpr (MMAX >= 2)  xor_pass<2>(ru, rv, lane);
    if constexpr (MMAX >= 1)  xor_pass<1>(ru, rv, lane);
    reg_tail_asc(ru);
    reg_tail_asc(rv);
}

// ---- cross mirror pass: (t,k) <-> (t^X, 31-k); keep_min at (t & (X+1)/2)==0.
//      Pairs (k, 31-k) handled jointly so reads precede writes (no hazard). ----
template<int X>
__device__ __forceinline__ void mirror_pass(float ru[V], float rv[V], int lane) {
    const bool keep_min = (lane & ((X + 1) >> 1)) == 0;
    if constexpr (X == 1) {
        #pragma unroll
        for (int k = 0; k < V / 2; ++k) {
            const int j = V - 1 - k;
            const float ua = dpp_x<0xB1>(ru[j]);
            const float ub = dpp_x<0xB1>(ru[k]);
            ru[k] = ce2(ru[k], ua, keep_min);
            ru[j] = ce2(ru[j], ub, keep_min);
            const float va = dpp_x<0xB1>(rv[j]);
            const float vb = dpp_x<0xB1>(rv[k]);
            rv[k] = ce2(rv[k], va, keep_min);
            rv[j] = ce2(rv[j], vb, keep_min);
        }
    } else {
        const int pa = (lane ^ X) << 2;
        #pragma unroll
        for (int k = 0; k < V / 2; ++k) {
            const int j = V - 1 - k;
            const float ua = bperm_x(pa, ru[j]);
            const float ub = bperm_x(pa, ru[k]);
            ru[k] = ce2(ru[k], ua, keep_min);
            ru[j] = ce2(ru[j], ub, keep_min);
            const float va = bperm_x(pa, rv[j]);
            const float vb = bperm_x(pa, rv[k]);
            rv[k] = ce2(rv[k], va, keep_min);
            rv[j] = ce2(rv[j], vb, keep_min);
        }
    }
}

// ---- full merge stage S (64..2048): cross mirror + cross descend + reg tail ----
template<int S>
__device__ __forceinline__ void stage_m(float ru[V], float rv[V], int lane) {
    mirror_pass<(S >> 5) - 1>(ru, rv, lane);   // X = S/32 - 1  (t-bit mirror mask)
    cross_descend<(S >> 7)>(ru, rv, lane);     // descend strides S/4..32 -> m = S/128..1
}

__global__ __launch_bounds__(THREADS, 4) void w1_rows_kernel(
    const float* __restrict__ pred,
    const float* __restrict__ tru,
    float* __restrict__ out,
    float scale)
{
    __shared__ float xbuf[THREADS * 33];   // 33792 B, stride 33 (2-way alias = free)
    __shared__ float wsum[THREADS / 64];

    const int tid  = threadIdx.x;
    const int t    = tid & 127;            // thread index within the row (0..127)
    const int lane = tid & 63;
    const int row  = blockIdx.x * 2 + (tid >> 7);
    const size_t base = (size_t)row * N_ELEM + (size_t)t * V;

    // Blocked layout: row-thread t owns global indices [32t, 32t+32).
    float ru[V], rv[V];
    {
        const float4* u4 = (const float4*)(pred + base);
        const float4* v4 = (const float4*)(tru  + base);
        #pragma unroll
        for (int c = 0; c < V / 4; ++c) {
            float4 a = u4[c], b = v4[c];
            ru[4*c+0] = a.x; ru[4*c+1] = a.y; ru[4*c+2] = a.z; ru[4*c+3] = a.w;
            rv[4*c+0] = b.x; rv[4*c+1] = b.y; rv[4*c+2] = b.z; rv[4*c+3] = b.w;
        }
    }

    // Stages S=2..32: fully in-register ascending sort of each 32-run.
    reg_merge<2>(ru);  reg_merge<2>(rv);
    reg_merge<4>(ru);  reg_merge<4>(rv);
    reg_merge<8>(ru);  reg_merge<8>(rv);
    reg_merge<16>(ru); reg_merge<16>(rv);
    reg_merge<32>(ru); reg_merge<32>(rv);

    // Stages S=64..2048: cross-lane mirror + descend, everything ascending.
    stage_m<64>(ru, rv, lane);
    stage_m<128>(ru, rv, lane);
    stage_m<256>(ru, rv, lane);
    stage_m<512>(ru, rv, lane);
    stage_m<1024>(ru, rv, lane);
    stage_m<2048>(ru, rv, lane);

    // Stage S=4096: mirror partner t^127 crosses the wave boundary -> LDS,
    // reading the partner's registers reversed (31-k). Then descend m=32..1.
    {
        const bool keep_min = (t & 64) == 0;
        const int  wb = tid * 33;
        const int  rb = (tid ^ 127) * 33;      // same row: bit7 preserved

        #pragma unroll
        for (int k = 0; k < V; ++k) xbuf[wb + k] = ru[k];
        __syncthreads();
        #pragma unroll
        for (int k = 0; k < V; ++k)
            ru[k] = ce2(ru[k], xbuf[rb + (V - 1 - k)], keep_min);
        __syncthreads();

        #pragma unroll
        for (int k = 0; k < V; ++k) xbuf[wb + k] = rv[k];
        __syncthreads();
        #pragma unroll
        for (int k = 0; k < V; ++k)
            rv[k] = ce2(rv[k], xbuf[rb + (V - 1 - k)], keep_min);
        // no barrier needed before register-only work below

        cross_descend<32>(ru, rv, lane);       // strides 1024..32 then reg tail
    }

    // Epilogue: per-thread |diff| sum, wave reduce, block reduce, one atomic.
    float part = 0.f;
    #pragma unroll
    for (int k = 0; k < V; ++k) part += fabsf(ru[k] - rv[k]);

    #pragma unroll
    for (int off = 32; off > 0; off >>= 1)
        part += __shfl_down(part, off, 64);

    const int wid = tid >> 6;
    if (lane == 0) wsum[wid] = part;
    __syncthreads();
    if (tid == 0) {
        float tot = wsum[0] + wsum[1] + wsum[2] + wsum[3];
        atomicAdd(out, tot * scale);
    }
}

extern "C" void kernel_launch(void* const* d_in, const int* in_sizes, int n_in,
                              void* d_out, int out_size, void* d_ws, size_t ws_size,
                              hipStream_t stream)
{
    (void)n_in; (void)out_size; (void)d_ws; (void)ws_size;

    const float* pred = (const float*)d_in[0];
    const float* tru  = (const float*)d_in[1];
    float* out = (float*)d_out;

    const int B = in_sizes[0] / N_ELEM;   // 4096 rows

    hipMemsetAsync(out, 0, sizeof(float), stream);

    const float scale = 1.0f / ((float)N_ELEM * (float)B);
    w1_rows_kernel<<<B / 2, THREADS, 0, stream>>>(pred, tru, out, scale);
}